// Round 5
// baseline (751.886 us; speedup 1.0000x reference)
//
#include <hip/hip_runtime.h>
#include <hip/hip_bf16.h>
#include <cstdint>

#define N_NODESC  102400
#define N_EDGESC  1638400
#define NUM_GRAPHS 128
#define NPG       800
#define HID       128
#define BN_EPS    1e-5f
#define NPR       12800      // nodes per dst-range (8 ranges)

typedef short short8 __attribute__((ext_vector_type(8)));
typedef float f32x4  __attribute__((ext_vector_type(4)));

__device__ __forceinline__ unsigned short f2bf(float f){
    union { __hip_bfloat16 h; unsigned short u; } cv;
    cv.h = __float2bfloat16(f);
    return cv.u;
}
__device__ __forceinline__ float bflo(unsigned int g){ return __uint_as_float(g << 16); }
__device__ __forceinline__ float bfhi(unsigned int g){ return __uint_as_float(g & 0xffff0000u); }
__device__ __forceinline__ float bfu(unsigned short u){ return __uint_as_float(((unsigned int)u) << 16); }

// slice stride: 4 slices of [N_NODESC+1][32] bf16 (dummy zero row at index N_NODESC)
#define SSTR_S ((size_t)(N_NODESC+1)*32)   // in shorts
#define SSTR_U ((size_t)(N_NODESC+1)*16)   // in uints

// ----------------- CSR build: range-partitioned (range = blockIdx&7 -> XCD-local writes) -----------------
__global__ __launch_bounds__(256) void k_count(const int* __restrict__ ei, int* __restrict__ deg){
    int b = blockIdx.x;
    int r = b & 7;
    int e = (b >> 3)*256 + threadIdx.x;
    int lo = r * NPR;
    int d = __builtin_nontemporal_load(&ei[N_EDGESC + e]);
    if (d >= lo && d < lo + NPR) atomicAdd(&deg[d], 1);
}

__global__ __launch_bounds__(1024) void k_scan_a(const int* __restrict__ deg, int* __restrict__ row_ptr,
                                                 float* __restrict__ dinv, int* __restrict__ chunkTot){
    __shared__ int sh[1024];
    int t = threadIdx.x;
    int i = blockIdx.x*1024 + t;
    int v = deg[i];
    dinv[i] = rsqrtf((float)(v + 1));   // +1 self loop
    sh[t] = v;
    __syncthreads();
    for (int off = 1; off < 1024; off <<= 1){
        int add = (t >= off) ? sh[t - off] : 0;
        __syncthreads();
        sh[t] += add;
        __syncthreads();
    }
    row_ptr[i] = sh[t] - v;
    if (t == 1023) chunkTot[blockIdx.x] = sh[t];
}

__global__ __launch_bounds__(128) void k_scan_b(const int* __restrict__ chunkTot, int* __restrict__ chunkOff,
                                                int* __restrict__ row_ptr){
    __shared__ int sh[128];
    int t = threadIdx.x;
    int v = (t < 100) ? chunkTot[t] : 0;
    sh[t] = v;
    __syncthreads();
    for (int off = 1; off < 128; off <<= 1){
        int add = (t >= off) ? sh[t - off] : 0;
        __syncthreads();
        sh[t] += add;
        __syncthreads();
    }
    if (t < 100) chunkOff[t] = sh[t] - v;
    if (t == 0)  row_ptr[N_NODESC] = N_EDGESC;
}

__global__ __launch_bounds__(1024) void k_scan_c(int* __restrict__ row_ptr, const int* __restrict__ chunkOff){
    int i = blockIdx.x*1024 + threadIdx.x;
    row_ptr[i] += chunkOff[blockIdx.x];
}

__global__ __launch_bounds__(256) void k_scatter(const int* __restrict__ ei, const int* __restrict__ row_ptr,
                                                 int* __restrict__ cursor, int* __restrict__ srcS){
    int b = blockIdx.x;
    int r = b & 7;
    int e = (b >> 3)*256 + threadIdx.x;
    int lo = r * NPR;
    int d = __builtin_nontemporal_load(&ei[N_EDGESC + e]);
    if (d >= lo && d < lo + NPR){
        int s = ei[e];
        int pos = row_ptr[d] + atomicAdd(&cursor[d], 1);
        srcS[pos] = s;
    }
}

// ----------------- W0^T in bf16 -----------------
__global__ __launch_bounds__(256) void k_prepw0(const float* __restrict__ W, unsigned short* __restrict__ Wt){
    int idx = blockIdx.x*256 + threadIdx.x;          // 16384 elements
    int n = idx & 127, k = idx >> 7;
    Wt[n*128 + k] = f2bf(W[k*128 + n]);
}

// ----------------- MFMA bf16 GEMM: Hd = bf16(dinv[row]*(X @ W + biasv)), channel-sliced output -----------------
// M=102400, N=K=128. 4 waves/block, wave computes 16 rows x 128 cols. No LDS.
template<int F32IN>
__global__ __launch_bounds__(256) void k_gemm_mfma(const void* __restrict__ Xin,
        const unsigned short* __restrict__ Wt, const float* __restrict__ biasv,
        const float* __restrict__ dinv, unsigned short* __restrict__ H){
    int l   = threadIdx.x & 63;
    int wid = threadIdx.x >> 6;
    int R   = blockIdx.x*64 + wid*16;
    int r0  = l & 15;          // A-row / B-col / D-col within fragment
    int kg  = l >> 4;          // 8-wide k group
    short8 a[4];
    if (F32IN){
        const float* X = (const float*)Xin;
        #pragma unroll
        for (int kk = 0; kk < 4; kk++){
            const float* p = X + (size_t)(R + r0)*HID + kk*32 + kg*8;
            float4 u = *(const float4*)p;
            float4 v = *(const float4*)(p + 4);
            short8 t;
            t[0]=(short)f2bf(u.x); t[1]=(short)f2bf(u.y); t[2]=(short)f2bf(u.z); t[3]=(short)f2bf(u.w);
            t[4]=(short)f2bf(v.x); t[5]=(short)f2bf(v.y); t[6]=(short)f2bf(v.z); t[7]=(short)f2bf(v.w);
            a[kk] = t;
        }
    } else {
        const unsigned short* X = (const unsigned short*)Xin;   // channel-sliced
        #pragma unroll
        for (int kk = 0; kk < 4; kk++)
            a[kk] = *(const short8*)(X + kk*SSTR_S + (size_t)(R + r0)*32 + kg*8);
    }
    f32x4 acc[8];
    #pragma unroll
    for (int i = 0; i < 8; i++) acc[i] = (f32x4)(0.f);
    #pragma unroll
    for (int kk = 0; kk < 4; kk++){
        #pragma unroll
        for (int nf = 0; nf < 8; nf++){
            short8 b = *(const short8*)(Wt + (size_t)(nf*16 + r0)*HID + kk*32 + kg*8);
            acc[nf] = __builtin_amdgcn_mfma_f32_16x16x32_bf16(a[kk], b, acc[nf], 0, 0, 0);
        }
    }
    float bv[8];
    #pragma unroll
    for (int nf = 0; nf < 8; nf++) bv[nf] = biasv[nf*16 + r0];
    #pragma unroll
    for (int r = 0; r < 4; r++){
        int row = R + kg*4 + r;
        float di = dinv[row];
        #pragma unroll
        for (int nf = 0; nf < 8; nf++)
            H[(nf>>1)*SSTR_S + (size_t)row*32 + (nf&1)*16 + r0] = f2bf(di * (acc[nf][r] + bv[nf]));
    }
}

// --------- channel-sliced aggregation + relu + fused BN stats ---------
// slice = (blockIdx&7)>>1 -> each XCD pair works one 6.5MB Hd slice (L2-resident)
// OUT[n] = relu( dinv[n] * (sum_e Hd[src_e] + Hd[n]) + b )
__global__ __launch_bounds__(256) void k_agg(const unsigned int* __restrict__ Hb, const int* __restrict__ row_ptr,
                                             const int* __restrict__ srcS, const float* __restrict__ dinv,
                                             const float* __restrict__ bconv,
                                             unsigned int* __restrict__ OUT, float* __restrict__ sum,
                                             float* __restrict__ sumsq){
    int lane = threadIdx.x & 63;
    int q    = lane >> 4;          // quarter: which edge in a 4-edge gather round
    int l16  = lane & 15;          // uint index within 32ch slice row (2 channels)
    int w    = threadIdx.x >> 6;
    int b    = blockIdx.x;
    int slice = (b & 7) >> 1;
    int widx  = (((b >> 3) << 1) | (b & 1))*4 + w;   // 0..2047 within slice group
    const unsigned int* Hs = Hb + slice*SSTR_U;
    unsigned int* Os = OUT + slice*SSTR_U;
    float2 bc = ((const float2*)bconv)[slice*16 + l16];
    float sx0=0.f, sx1=0.f, sq0=0.f, sq1=0.f;
    for (int n = widx; n < N_NODESC; n += 2048){
        int e0 = row_ptr[n], e1 = row_ptr[n+1];
        float a0 = 0.f, a1 = 0.f;
        int e = e0;
        // 16 edges per round: quarter q owns edges e+4q..e+4q+3 -> 16 lines in flight
        for (; e + 16 <= e1; e += 16){
            int base = e + q*4;
            int s0 = srcS[base], s1 = srcS[base+1], s2 = srcS[base+2], s3 = srcS[base+3];
            unsigned int g0 = Hs[(size_t)s0*16 + l16];
            unsigned int g1 = Hs[(size_t)s1*16 + l16];
            unsigned int g2 = Hs[(size_t)s2*16 + l16];
            unsigned int g3 = Hs[(size_t)s3*16 + l16];
            a0 += bflo(g0); a1 += bfhi(g0);
            a0 += bflo(g1); a1 += bfhi(g1);
            a0 += bflo(g2); a1 += bfhi(g2);
            a0 += bflo(g3); a1 += bfhi(g3);
        }
        for (; e + 4 <= e1; e += 4){
            int s = srcS[e + q];
            unsigned int g = Hs[(size_t)s*16 + l16];
            a0 += bflo(g); a1 += bfhi(g);
        }
        {   // tail (0-3 edges) + self-loop + dummy padding in one round
            int idx = e + q;
            int s = (idx < e1) ? srcS[idx] : ((idx == e1) ? n : N_NODESC);
            unsigned int g = Hs[(size_t)s*16 + l16];
            a0 += bflo(g); a1 += bfhi(g);
        }
        a0 += __shfl_xor(a0, 16); a1 += __shfl_xor(a1, 16);
        a0 += __shfl_xor(a0, 32); a1 += __shfl_xor(a1, 32);
        if (q == 0){
            float dn = dinv[n];
            a0 = fmaxf(fmaf(a0, dn, bc.x), 0.f);
            a1 = fmaxf(fmaf(a1, dn, bc.y), 0.f);
            unsigned int o = ((unsigned int)f2bf(a1) << 16) | (unsigned int)f2bf(a0);
            __builtin_nontemporal_store(o, &Os[(size_t)n*16 + l16]);
            sx0 += a0; sq0 = fmaf(a0,a0,sq0);
            sx1 += a1; sq1 = fmaf(a1,a1,sq1);
        }
    }
    __shared__ float shs[4][32];
    __shared__ float shq[4][32];
    if (lane < 16){
        shs[w][2*l16]   = sx0; shs[w][2*l16+1] = sx1;
        shq[w][2*l16]   = sq0; shq[w][2*l16+1] = sq1;
    }
    __syncthreads();
    int t = threadIdx.x;
    if (t < 32){
        atomicAdd(&sum[slice*32 + t],   shs[0][t] + shs[1][t] + shs[2][t] + shs[3][t]);
        atomicAdd(&sumsq[slice*32 + t], shq[0][t] + shq[1][t] + shq[2][t] + shq[3][t]);
    }
}

// ----------------- BN finalize + fold into next W (emits transposed bf16 W' + bias) -----------------
__global__ __launch_bounds__(128) void k_finalize(const float* __restrict__ sum, const float* __restrict__ sumsq,
                                                  const float* __restrict__ gamma, const float* __restrict__ beta,
                                                  const float* __restrict__ Wnext, float* __restrict__ A,
                                                  float* __restrict__ B, unsigned short* __restrict__ WpT,
                                                  float* __restrict__ biasv, int hasNext){
    __shared__ float Ash[128], Bsh[128];
    int c = threadIdx.x;
    const float invN = 1.0f / (float)N_NODESC;
    float mu  = sum[c] * invN;
    float var = sumsq[c] * invN - mu*mu;
    float is  = rsqrtf(var + BN_EPS);
    float a = is * gamma[c];
    float b = beta[c] - mu * a;
    A[c] = a; B[c] = b; Ash[c] = a; Bsh[c] = b;
    __syncthreads();
    if (hasNext){
        float bv = 0.f;
        for (int k = 0; k < 128; k++){
            float w = Wnext[k*128 + c];
            WpT[c*128 + k] = f2bf(Ash[k] * w);   // W'^T[n][k] = A[k]*W[k][n]
            bv = fmaf(Bsh[k], w, bv);
        }
        biasv[c] = bv;
    }
}

// ----------------- readout pooling (max, mean, first), sliced bf16 in, BN applied inline -----------------
__global__ __launch_bounds__(1024) void k_pool(const unsigned short* __restrict__ X, const float* __restrict__ A,
                                               const float* __restrict__ B, float* __restrict__ g){
    __shared__ float shm[8][128];
    __shared__ float shs[8][128];
    int t = threadIdx.x;
    int c = t & 127, sl = t >> 7;    // 8 slices x 100 nodes
    int gr = blockIdx.x;
    int cs = c >> 5, lc = c & 31;
    float a = A[c], b = B[c];
    const unsigned short* base = X + cs*SSTR_S + ((size_t)gr*NPG + sl*100)*32 + lc;
    float mx = -1e30f, sm = 0.f;
    for (int i = 0; i < 100; i++){
        float v = fmaf(bfu(base[(size_t)i*32]), a, b);
        mx = fmaxf(mx, v); sm += v;
    }
    shm[sl][c] = mx; shs[sl][c] = sm;
    if (sl == 0) g[gr*384 + 256 + c] = fmaf(bfu(base[0]), a, b);   // first node
    __syncthreads();
    if (t < 128){
        float m = shm[0][t], s = shs[0][t];
        #pragma unroll
        for (int qq = 1; qq < 8; qq++){ m = fmaxf(m, shm[qq][t]); s += shs[qq][t]; }
        g[gr*384 + t]       = m;
        g[gr*384 + 128 + t] = s * (1.0f/(float)NPG);
    }
}

// ----------------- MLP + log_softmax -----------------
__global__ __launch_bounds__(512) void k_mlp(const float* __restrict__ g, const float* __restrict__ W1,
                                             const float* __restrict__ b1, const float* __restrict__ W2,
                                             const float* __restrict__ b2, float* __restrict__ out){
    __shared__ float row[384];
    __shared__ float t1[384];
    __shared__ float r0[512], r1[512];
    int t = threadIdx.x, gr = blockIdx.x;
    if (t < 384) row[t] = g[gr*384 + t];
    __syncthreads();
    if (t < 384){
        float acc = b1[t];
        for (int k = 0; k < 384; k++) acc = fmaf(row[k], W1[(size_t)k*384 + t], acc);
        t1[t] = acc;
    }
    __syncthreads();
    float p0 = 0.f, p1 = 0.f;
    if (t < 384){ float v = t1[t]; p0 = v*W2[t*2]; p1 = v*W2[t*2+1]; }
    r0[t] = p0; r1[t] = p1; __syncthreads();
    for (int off = 256; off > 0; off >>= 1){
        if (t < off){ r0[t] += r0[t+off]; r1[t] += r1[t+off]; }
        __syncthreads();
    }
    if (t == 0){
        float o0 = r0[0] + b2[0], o1 = r1[0] + b2[1];
        float m = fmaxf(o0, o1);
        float lse = m + logf(expf(o0 - m) + expf(o1 - m));
        out[gr*2 + 0] = o0 - lse;
        out[gr*2 + 1] = o1 - lse;
    }
}

extern "C" void kernel_launch(void* const* d_in, const int* in_sizes, int n_in,
                              void* d_out, int out_size, void* d_ws, size_t ws_size,
                              hipStream_t stream){
    const float* x     = (const float*)d_in[0];
    const int*   ei    = (const int*)d_in[1];
    const float* Wconv = (const float*)d_in[3];
    const float* bconv = (const float*)d_in[4];
    const float* gamma = (const float*)d_in[5];
    const float* beta  = (const float*)d_in[6];
    const float* W1    = (const float*)d_in[7];
    const float* b1    = (const float*)d_in[8];
    const float* W2    = (const float*)d_in[9];
    const float* b2    = (const float*)d_in[10];
    float* out = (float*)d_out;

    char* p = (char*)d_ws;
    size_t off = 0;
    auto alloc = [&](size_t bytes)->char* {
        char* r = p + off; off += (bytes + 255) & ~(size_t)255; return r;
    };
    unsigned short* buf1 = (unsigned short*)alloc(SSTR_S*4*2); // Hd, 4 channel slices (+dummy rows)
    unsigned short* buf2 = (unsigned short*)alloc(SSTR_S*4*2); // post-agg relu'd, sliced
    int*   srcS    = (int*)  alloc((size_t)N_EDGESC*4);
    int*   row_ptr = (int*)  alloc((size_t)(N_NODESC+1)*4);
    int*   deg     = (int*)  alloc((size_t)N_NODESC*4);      // reused as scatter cursor
    float* dinv    = (float*)alloc((size_t)N_NODESC*4);
    int*   chunkTot= (int*)  alloc(512);
    int*   chunkOff= (int*)  alloc(512);
    float* stats   = (float*)alloc(3*2*128*4);               // [l][sum|sumsq][128]
    float* AB      = (float*)alloc(3*2*128*4);               // [l][A|B][128]
    unsigned short* Wt0 = (unsigned short*)alloc(128*128*2); // bf16 W0^T
    unsigned short* WpT = (unsigned short*)alloc(128*128*2); // bf16 BN-folded next-layer W^T
    float* biasv   = (float*)alloc(512);
    float* g       = (float*)alloc((size_t)NUM_GRAPHS*384*4);
    (void)ws_size; (void)in_sizes; (void)n_in; (void)out_size;

    hipMemsetAsync(deg,   0, (size_t)N_NODESC*4, stream);
    hipMemsetAsync(stats, 0, 3*2*128*4, stream);
    hipMemsetAsync(biasv, 0, 512, stream);
    for (int s = 0; s < 4; s++)   // dummy zero row per slice
        hipMemsetAsync(buf1 + s*SSTR_S + (size_t)N_NODESC*32, 0, 64, stream);

    k_count  <<<(N_EDGESC/256)*8, 256, 0, stream>>>(ei, deg);
    k_scan_a <<<N_NODESC/1024, 1024, 0, stream>>>(deg, row_ptr, dinv, chunkTot);
    k_scan_b <<<1, 128, 0, stream>>>(chunkTot, chunkOff, row_ptr);
    k_scan_c <<<N_NODESC/1024, 1024, 0, stream>>>(row_ptr, chunkOff);
    hipMemsetAsync(deg, 0, (size_t)N_NODESC*4, stream);      // cursor for scatter
    k_scatter<<<(N_EDGESC/256)*8, 256, 0, stream>>>(ei, row_ptr, deg, srcS);
    k_prepw0 <<<64, 256, 0, stream>>>(Wconv, Wt0);

    for (int l = 0; l < 3; l++){
        if (l == 0)
            k_gemm_mfma<1><<<N_NODESC/64, 256, 0, stream>>>((const void*)x, Wt0, biasv, dinv, buf1);
        else
            k_gemm_mfma<0><<<N_NODESC/64, 256, 0, stream>>>((const void*)buf2, WpT, biasv, dinv, buf1);
        k_agg<<<2048, 256, 0, stream>>>((const unsigned int*)buf1, row_ptr, srcS, dinv,
                                        bconv + l*HID, (unsigned int*)buf2,
                                        stats + l*256, stats + l*256 + 128);
        k_finalize<<<1, 128, 0, stream>>>(stats + l*256, stats + l*256 + 128,
                                          gamma + l*HID, beta + l*HID,
                                          Wconv + (size_t)(l+1 < 3 ? l+1 : 0)*HID*HID,
                                          AB + l*256, AB + l*256 + 128,
                                          WpT, biasv, (l < 2) ? 1 : 0);
    }
    k_pool<<<NUM_GRAPHS, 1024, 0, stream>>>(buf2, AB + 2*256, AB + 2*256 + 128, g);
    k_mlp <<<NUM_GRAPHS, 512, 0, stream>>>(g, W1, b1, W2, b2, out);
}

// Round 6
// 689.600 us; speedup vs baseline: 1.0903x; 1.0903x over previous
//
#include <hip/hip_runtime.h>
#include <hip/hip_bf16.h>
#include <cstdint>

#define N_NODESC  102400
#define N_EDGESC  1638400
#define NUM_GRAPHS 128
#define NPG       800
#define HID       128
#define BN_EPS    1e-5f
#define NPR       12800      // nodes per dst-range (8 ranges)

typedef short short8 __attribute__((ext_vector_type(8)));
typedef float f32x4  __attribute__((ext_vector_type(4)));

__device__ __forceinline__ unsigned short f2bf(float f){
    union { __hip_bfloat16 h; unsigned short u; } cv;
    cv.h = __float2bfloat16(f);
    return cv.u;
}
__device__ __forceinline__ float bflo(unsigned int g){ return __uint_as_float(g << 16); }
__device__ __forceinline__ float bfhi(unsigned int g){ return __uint_as_float(g & 0xffff0000u); }
__device__ __forceinline__ float bfu(unsigned short u){ return __uint_as_float(((unsigned int)u) << 16); }

// ----------------- CSR build: range-partitioned (range = blockIdx&7 -> XCD-local atomics/writes) -----------------
__global__ __launch_bounds__(256) void k_count(const int* __restrict__ ei, int* __restrict__ deg){
    int b = blockIdx.x;
    int r = b & 7;
    int e = (b >> 3)*256 + threadIdx.x;
    int lo = r * NPR;
    int d = __builtin_nontemporal_load(&ei[N_EDGESC + e]);
    if (d >= lo && d < lo + NPR) atomicAdd(&deg[d], 1);
}

__global__ __launch_bounds__(1024) void k_scan_a(const int* __restrict__ deg, int* __restrict__ row_ptr,
                                                 float* __restrict__ dinv, int* __restrict__ chunkTot){
    __shared__ int sh[1024];
    int t = threadIdx.x;
    int i = blockIdx.x*1024 + t;
    int v = deg[i];
    dinv[i] = rsqrtf((float)(v + 1));   // +1 self loop
    sh[t] = v;
    __syncthreads();
    for (int off = 1; off < 1024; off <<= 1){
        int add = (t >= off) ? sh[t - off] : 0;
        __syncthreads();
        sh[t] += add;
        __syncthreads();
    }
    row_ptr[i] = sh[t] - v;
    if (t == 1023) chunkTot[blockIdx.x] = sh[t];
}

__global__ __launch_bounds__(128) void k_scan_b(const int* __restrict__ chunkTot, int* __restrict__ chunkOff,
                                                int* __restrict__ row_ptr){
    __shared__ int sh[128];
    int t = threadIdx.x;
    int v = (t < 100) ? chunkTot[t] : 0;
    sh[t] = v;
    __syncthreads();
    for (int off = 1; off < 128; off <<= 1){
        int add = (t >= off) ? sh[t - off] : 0;
        __syncthreads();
        sh[t] += add;
        __syncthreads();
    }
    if (t < 100) chunkOff[t] = sh[t] - v;
    if (t == 0)  row_ptr[N_NODESC] = N_EDGESC;
}

__global__ __launch_bounds__(1024) void k_scan_c(int* __restrict__ row_ptr, const int* __restrict__ chunkOff){
    int i = blockIdx.x*1024 + threadIdx.x;
    row_ptr[i] += chunkOff[blockIdx.x];
}

__global__ __launch_bounds__(256) void k_scatter(const int* __restrict__ ei, const int* __restrict__ row_ptr,
                                                 int* __restrict__ cursor, const float* __restrict__ dinv,
                                                 int* __restrict__ srcS, float* __restrict__ normS){
    int b = blockIdx.x;
    int r = b & 7;
    int e = (b >> 3)*256 + threadIdx.x;
    int lo = r * NPR;
    int d = __builtin_nontemporal_load(&ei[N_EDGESC + e]);
    if (d >= lo && d < lo + NPR){
        int s = ei[e];
        int pos = row_ptr[d] + atomicAdd(&cursor[d], 1);
        srcS[pos]  = s;
        normS[pos] = dinv[s] * dinv[d];
    }
}

// ----------------- W0^T in bf16 -----------------
__global__ __launch_bounds__(256) void k_prepw0(const float* __restrict__ W, unsigned short* __restrict__ Wt){
    int idx = blockIdx.x*256 + threadIdx.x;          // 16384 elements
    int n = idx & 127, k = idx >> 7;
    Wt[n*128 + k] = f2bf(W[k*128 + n]);
}

// ----------------- MFMA bf16 GEMM: H = bf16(X @ W + biasv), W given as Wt[n][k] bf16 -----------------
// M=102400, N=K=128. 4 waves/block, wave computes 16 rows x 128 cols. No LDS.
template<int F32IN>
__global__ __launch_bounds__(256) void k_gemm_mfma(const void* __restrict__ Xin,
        const unsigned short* __restrict__ Wt, const float* __restrict__ biasv,
        unsigned short* __restrict__ H){
    int l   = threadIdx.x & 63;
    int wid = threadIdx.x >> 6;
    int R   = blockIdx.x*64 + wid*16;
    int r0  = l & 15;          // A-row / B-col / D-col within fragment
    int kg  = l >> 4;          // 8-wide k group
    short8 a[4];
    if (F32IN){
        const float* X = (const float*)Xin;
        #pragma unroll
        for (int kk = 0; kk < 4; kk++){
            const float* p = X + (size_t)(R + r0)*HID + kk*32 + kg*8;
            float4 u = *(const float4*)p;
            float4 v = *(const float4*)(p + 4);
            short8 t;
            t[0]=(short)f2bf(u.x); t[1]=(short)f2bf(u.y); t[2]=(short)f2bf(u.z); t[3]=(short)f2bf(u.w);
            t[4]=(short)f2bf(v.x); t[5]=(short)f2bf(v.y); t[6]=(short)f2bf(v.z); t[7]=(short)f2bf(v.w);
            a[kk] = t;
        }
    } else {
        const unsigned short* X = (const unsigned short*)Xin;
        #pragma unroll
        for (int kk = 0; kk < 4; kk++)
            a[kk] = *(const short8*)(X + (size_t)(R + r0)*HID + kk*32 + kg*8);
    }
    f32x4 acc[8];
    #pragma unroll
    for (int i = 0; i < 8; i++) acc[i] = (f32x4)(0.f);
    #pragma unroll
    for (int kk = 0; kk < 4; kk++){
        #pragma unroll
        for (int nf = 0; nf < 8; nf++){
            short8 b = *(const short8*)(Wt + (size_t)(nf*16 + r0)*HID + kk*32 + kg*8);
            acc[nf] = __builtin_amdgcn_mfma_f32_16x16x32_bf16(a[kk], b, acc[nf], 0, 0, 0);
        }
    }
    #pragma unroll
    for (int nf = 0; nf < 8; nf++){
        float bv = biasv[nf*16 + r0];
        #pragma unroll
        for (int r = 0; r < 4; r++){
            int row = R + kg*4 + r;
            H[(size_t)row*HID + nf*16 + r0] = f2bf(acc[nf][r] + bv);
        }
    }
}

// --------- aggregation + relu + fused BN stats; bf16 in (pairs), bf16 out (pairs) ---------
__global__ __launch_bounds__(256) void k_agg(const unsigned int* __restrict__ Hb, const int* __restrict__ row_ptr,
                                             const int* __restrict__ srcS, const float* __restrict__ normS,
                                             const float* __restrict__ dinv, const float* __restrict__ bconv,
                                             unsigned int* __restrict__ OUT, float* __restrict__ sum,
                                             float* __restrict__ sumsq){
    int lane = threadIdx.x & 63;
    int w    = threadIdx.x >> 6;
    int wave = blockIdx.x*4 + w;
    int nw   = gridDim.x*4;
    float2 bc = ((const float2*)bconv)[lane];
    float sx0 = 0.f, sx1 = 0.f, sq0 = 0.f, sq1 = 0.f;
    for (int n = wave; n < N_NODESC; n += nw){
        int e0 = row_ptr[n], e1 = row_ptr[n+1];
        float ax = 0.f, ay = 0.f;
        int e = e0;
        while (e < e1 && (e & 3)){
            int s = srcS[e]; float nv = normS[e];
            unsigned int g = Hb[(size_t)s*64 + lane];
            ax = fmaf(nv, bflo(g), ax); ay = fmaf(nv, bfhi(g), ay);
            e++;
        }
        for (; e + 8 <= e1; e += 8){
            int4   sa = *(const int4*)(srcS + e);
            int4   sb = *(const int4*)(srcS + e + 4);
            float4 na = *(const float4*)(normS + e);
            float4 nb = *(const float4*)(normS + e + 4);
            unsigned int g0 = Hb[(size_t)sa.x*64 + lane];
            unsigned int g1 = Hb[(size_t)sa.y*64 + lane];
            unsigned int g2 = Hb[(size_t)sa.z*64 + lane];
            unsigned int g3 = Hb[(size_t)sa.w*64 + lane];
            unsigned int g4 = Hb[(size_t)sb.x*64 + lane];
            unsigned int g5 = Hb[(size_t)sb.y*64 + lane];
            unsigned int g6 = Hb[(size_t)sb.z*64 + lane];
            unsigned int g7 = Hb[(size_t)sb.w*64 + lane];
            ax = fmaf(na.x, bflo(g0), ax); ay = fmaf(na.x, bfhi(g0), ay);
            ax = fmaf(na.y, bflo(g1), ax); ay = fmaf(na.y, bfhi(g1), ay);
            ax = fmaf(na.z, bflo(g2), ax); ay = fmaf(na.z, bfhi(g2), ay);
            ax = fmaf(na.w, bflo(g3), ax); ay = fmaf(na.w, bfhi(g3), ay);
            ax = fmaf(nb.x, bflo(g4), ax); ay = fmaf(nb.x, bfhi(g4), ay);
            ax = fmaf(nb.y, bflo(g5), ax); ay = fmaf(nb.y, bfhi(g5), ay);
            ax = fmaf(nb.z, bflo(g6), ax); ay = fmaf(nb.z, bfhi(g6), ay);
            ax = fmaf(nb.w, bflo(g7), ax); ay = fmaf(nb.w, bfhi(g7), ay);
        }
        if (e + 4 <= e1){
            int4   sa = *(const int4*)(srcS + e);
            float4 na = *(const float4*)(normS + e);
            unsigned int g0 = Hb[(size_t)sa.x*64 + lane];
            unsigned int g1 = Hb[(size_t)sa.y*64 + lane];
            unsigned int g2 = Hb[(size_t)sa.z*64 + lane];
            unsigned int g3 = Hb[(size_t)sa.w*64 + lane];
            ax = fmaf(na.x, bflo(g0), ax); ay = fmaf(na.x, bfhi(g0), ay);
            ax = fmaf(na.y, bflo(g1), ax); ay = fmaf(na.y, bfhi(g1), ay);
            ax = fmaf(na.z, bflo(g2), ax); ay = fmaf(na.z, bfhi(g2), ay);
            ax = fmaf(na.w, bflo(g3), ax); ay = fmaf(na.w, bfhi(g3), ay);
            e += 4;
        }
        for (; e < e1; e++){
            int s = srcS[e]; float nv = normS[e];
            unsigned int g = Hb[(size_t)s*64 + lane];
            ax = fmaf(nv, bflo(g), ax); ay = fmaf(nv, bfhi(g), ay);
        }
        float di = dinv[n]; float ws = di*di;
        unsigned int gn = Hb[(size_t)n*64 + lane];
        ax = fmaf(ws, bflo(gn), ax); ay = fmaf(ws, bfhi(gn), ay);
        ax = fmaxf(ax + bc.x, 0.f); ay = fmaxf(ay + bc.y, 0.f);
        unsigned int o = ((unsigned int)f2bf(ay) << 16) | (unsigned int)f2bf(ax);
        __builtin_nontemporal_store(o, &OUT[(size_t)n*64 + lane]);
        sx0 += ax; sq0 = fmaf(ax, ax, sq0);
        sx1 += ay; sq1 = fmaf(ay, ay, sq1);
    }
    __shared__ float shs[4][128];
    __shared__ float shq[4][128];
    shs[w][2*lane]   = sx0; shs[w][2*lane+1] = sx1;
    shq[w][2*lane]   = sq0; shq[w][2*lane+1] = sq1;
    __syncthreads();
    int t = threadIdx.x;
    if (t < 128){
        atomicAdd(&sum[t],   shs[0][t] + shs[1][t] + shs[2][t] + shs[3][t]);
        atomicAdd(&sumsq[t], shq[0][t] + shq[1][t] + shq[2][t] + shq[3][t]);
    }
}

// ----------------- BN finalize part 1: A, B, folded bias (1 block) -----------------
__global__ __launch_bounds__(128) void k_fin1(const float* __restrict__ sum, const float* __restrict__ sumsq,
                                              const float* __restrict__ gamma, const float* __restrict__ beta,
                                              const float* __restrict__ Wnext, float* __restrict__ A,
                                              float* __restrict__ B, float* __restrict__ biasv, int hasNext){
    __shared__ float Bsh[128];
    int c = threadIdx.x;
    const float invN = 1.0f / (float)N_NODESC;
    float mu  = sum[c] * invN;
    float var = sumsq[c] * invN - mu*mu;
    float is  = rsqrtf(var + BN_EPS);
    float a = is * gamma[c];
    float b = beta[c] - mu * a;
    A[c] = a; B[c] = b; Bsh[c] = b;
    __syncthreads();
    if (hasNext){
        float bv = 0.f;
        for (int k = 0; k < 128; k++)
            bv = fmaf(Bsh[k], Wnext[k*128 + c], bv);
        biasv[c] = bv;
    }
}

// ----------------- BN finalize part 2: parallel W fold, WpT[c][k] = bf16(A[k]*W[k][c]) -----------------
__global__ __launch_bounds__(256) void k_fin2(const float* __restrict__ A, const float* __restrict__ Wnext,
                                              unsigned short* __restrict__ WpT){
    int idx = blockIdx.x*256 + threadIdx.x;   // 16384
    int c = idx >> 7, k = idx & 127;
    WpT[c*128 + k] = f2bf(A[k] * Wnext[k*128 + c]);
}

// ----------------- readout pooling (max, mean, first), bf16 in, BN applied inline -----------------
__global__ __launch_bounds__(1024) void k_pool(const unsigned short* __restrict__ X, const float* __restrict__ A,
                                               const float* __restrict__ B, float* __restrict__ g){
    __shared__ float shm[8][128];
    __shared__ float shs[8][128];
    int t = threadIdx.x;
    int c = t & 127, sl = t >> 7;    // 8 slices x 100 nodes
    int gr = blockIdx.x;
    float a = A[c], b = B[c];
    const unsigned short* base = X + ((size_t)gr*NPG + sl*100)*HID;
    float mx = -1e30f, sm = 0.f;
    for (int i = 0; i < 100; i++){
        float v = fmaf(bfu(base[(size_t)i*HID + c]), a, b);
        mx = fmaxf(mx, v); sm += v;
    }
    shm[sl][c] = mx; shs[sl][c] = sm;
    if (sl == 0) g[gr*384 + 256 + c] = fmaf(bfu(base[c]), a, b);   // first node
    __syncthreads();
    if (t < 128){
        float m = shm[0][t], s = shs[0][t];
        #pragma unroll
        for (int q = 1; q < 8; q++){ m = fmaxf(m, shm[q][t]); s += shs[q][t]; }
        g[gr*384 + t]       = m;
        g[gr*384 + 128 + t] = s * (1.0f/(float)NPG);
    }
}

// ----------------- MLP + log_softmax -----------------
__global__ __launch_bounds__(512) void k_mlp(const float* __restrict__ g, const float* __restrict__ W1,
                                             const float* __restrict__ b1, const float* __restrict__ W2,
                                             const float* __restrict__ b2, float* __restrict__ out){
    __shared__ float row[384];
    __shared__ float t1[384];
    __shared__ float r0[512], r1[512];
    int t = threadIdx.x, gr = blockIdx.x;
    if (t < 384) row[t] = g[gr*384 + t];
    __syncthreads();
    if (t < 384){
        float acc = b1[t];
        for (int k = 0; k < 384; k++) acc = fmaf(row[k], W1[(size_t)k*384 + t], acc);
        t1[t] = acc;
    }
    __syncthreads();
    float p0 = 0.f, p1 = 0.f;
    if (t < 384){ float v = t1[t]; p0 = v*W2[t*2]; p1 = v*W2[t*2+1]; }
    r0[t] = p0; r1[t] = p1; __syncthreads();
    for (int off = 256; off > 0; off >>= 1){
        if (t < off){ r0[t] += r0[t+off]; r1[t] += r1[t+off]; }
        __syncthreads();
    }
    if (t == 0){
        float o0 = r0[0] + b2[0], o1 = r1[0] + b2[1];
        float m = fmaxf(o0, o1);
        float lse = m + logf(expf(o0 - m) + expf(o1 - m));
        out[gr*2 + 0] = o0 - lse;
        out[gr*2 + 1] = o1 - lse;
    }
}

extern "C" void kernel_launch(void* const* d_in, const int* in_sizes, int n_in,
                              void* d_out, int out_size, void* d_ws, size_t ws_size,
                              hipStream_t stream){
    const float* x     = (const float*)d_in[0];
    const int*   ei    = (const int*)d_in[1];
    const float* Wconv = (const float*)d_in[3];
    const float* bconv = (const float*)d_in[4];
    const float* gamma = (const float*)d_in[5];
    const float* beta  = (const float*)d_in[6];
    const float* W1    = (const float*)d_in[7];
    const float* b1    = (const float*)d_in[8];
    const float* W2    = (const float*)d_in[9];
    const float* b2    = (const float*)d_in[10];
    float* out = (float*)d_out;

    char* p = (char*)d_ws;
    size_t off = 0;
    auto alloc = [&](size_t bytes)->char* {
        char* r = p + off; off += (bytes + 255) & ~(size_t)255; return r;
    };
    unsigned short* buf1 = (unsigned short*)alloc((size_t)N_NODESC*HID*2);  // h = bf16(x@W)
    unsigned short* buf2 = (unsigned short*)alloc((size_t)N_NODESC*HID*2);  // post-agg relu'd bf16
    int*   srcS    = (int*)  alloc((size_t)N_EDGESC*4);
    float* normS   = (float*)alloc((size_t)N_EDGESC*4);
    int*   row_ptr = (int*)  alloc((size_t)(N_NODESC+1)*4);
    int*   deg     = (int*)  alloc((size_t)N_NODESC*4);      // reused as scatter cursor
    float* dinv    = (float*)alloc((size_t)N_NODESC*4);
    int*   chunkTot= (int*)  alloc(512);
    int*   chunkOff= (int*)  alloc(512);
    float* stats   = (float*)alloc(3*2*128*4);               // [l][sum|sumsq][128]
    float* AB      = (float*)alloc(3*2*128*4);               // [l][A|B][128]
    unsigned short* Wt0 = (unsigned short*)alloc(128*128*2); // bf16 W0^T
    unsigned short* WpT = (unsigned short*)alloc(128*128*2); // bf16 BN-folded next-layer W^T
    float* biasv   = (float*)alloc(512);
    float* g       = (float*)alloc((size_t)NUM_GRAPHS*384*4);
    (void)ws_size; (void)in_sizes; (void)n_in; (void)out_size;

    hipMemsetAsync(deg,   0, (size_t)N_NODESC*4, stream);
    hipMemsetAsync(stats, 0, 3*2*128*4, stream);
    hipMemsetAsync(biasv, 0, 512, stream);

    k_count  <<<(N_EDGESC/256)*8, 256, 0, stream>>>(ei, deg);
    k_scan_a <<<N_NODESC/1024, 1024, 0, stream>>>(deg, row_ptr, dinv, chunkTot);
    k_scan_b <<<1, 128, 0, stream>>>(chunkTot, chunkOff, row_ptr);
    k_scan_c <<<N_NODESC/1024, 1024, 0, stream>>>(row_ptr, chunkOff);
    hipMemsetAsync(deg, 0, (size_t)N_NODESC*4, stream);      // cursor for scatter
    k_scatter<<<(N_EDGESC/256)*8, 256, 0, stream>>>(ei, row_ptr, deg, dinv, srcS, normS);
    k_prepw0 <<<64, 256, 0, stream>>>(Wconv, Wt0);

    for (int l = 0; l < 3; l++){
        if (l == 0)
            k_gemm_mfma<1><<<N_NODESC/64, 256, 0, stream>>>((const void*)x, Wt0, biasv, buf1);
        else
            k_gemm_mfma<0><<<N_NODESC/64, 256, 0, stream>>>((const void*)buf2, WpT, biasv, buf1);
        k_agg<<<2048, 256, 0, stream>>>((const unsigned int*)buf1, row_ptr, srcS, normS, dinv,
                                        bconv + l*HID, (unsigned int*)buf2,
                                        stats + l*256, stats + l*256 + 128);
        k_fin1<<<1, 128, 0, stream>>>(stats + l*256, stats + l*256 + 128,
                                      gamma + l*HID, beta + l*HID,
                                      Wconv + (size_t)(l+1 < 3 ? l+1 : 0)*HID*HID,
                                      AB + l*256, AB + l*256 + 128,
                                      biasv, (l < 2) ? 1 : 0);
        if (l < 2)
            k_fin2<<<64, 256, 0, stream>>>(AB + l*256,
                                           Wconv + (size_t)(l+1)*HID*HID, WpT);
    }
    k_pool<<<NUM_GRAPHS, 1024, 0, stream>>>(buf2, AB + 2*256, AB + 2*256 + 128, g);
    k_mlp <<<NUM_GRAPHS, 512, 0, stream>>>(g, W1, b1, W2, b2, out);
}

// Round 8
// 546.186 us; speedup vs baseline: 1.3766x; 1.2626x over previous
//
#include <hip/hip_runtime.h>
#include <hip/hip_bf16.h>
#include <cstdint>

#define N_NODESC  102400
#define N_EDGESC  1638400
#define NUM_GRAPHS 128
#define NPG       800
#define HID       128
#define BN_EPS    1e-5f

#define NFINE 1600           // fine buckets of 64 nodes
#define NCOARSE 25           // coarse buckets of 4096 nodes
#define ROUND 2048           // edges per binning round

typedef short short8 __attribute__((ext_vector_type(8)));
typedef float f32x4  __attribute__((ext_vector_type(4)));
typedef unsigned long long u64;

__device__ __forceinline__ unsigned short f2bf(float f){
    union { __hip_bfloat16 h; unsigned short u; } cv;
    cv.h = __float2bfloat16(f);
    return cv.u;
}
__device__ __forceinline__ float bflo(unsigned int g){ return __uint_as_float(g << 16); }
__device__ __forceinline__ float bfhi(unsigned int g){ return __uint_as_float(g & 0xffff0000u); }
__device__ __forceinline__ float bfu(unsigned short u){ return __uint_as_float(((unsigned int)u) << 16); }

// ----------------- sort pass 0: fine histogram (1600 buckets of 64 dst nodes) -----------------
__global__ __launch_bounds__(256) void k_h1(const int* __restrict__ ei, int* __restrict__ fineCount){
    __shared__ int h[NFINE];
    int t = threadIdx.x;
    for (int i = t; i < NFINE; i += 256) h[i] = 0;
    __syncthreads();
    for (int e = blockIdx.x*256 + t; e < N_EDGESC; e += gridDim.x*256){
        int d = __builtin_nontemporal_load(&ei[N_EDGESC + e]);
        atomicAdd(&h[d >> 6], 1);
    }
    __syncthreads();
    for (int i = t; i < NFINE; i += 256) if (h[i]) atomicAdd(&fineCount[i], h[i]);
}

// ----------------- sort pass 0b: scan 1600 counts -> bases + cursors (1 block) -----------------
__global__ __launch_bounds__(256) void k_scanF(const int* __restrict__ fineCount, int* __restrict__ fineBase,
                                               int* __restrict__ fineCursor, int* __restrict__ coarseCursor){
    __shared__ int part[256];
    __shared__ int shb[NFINE];
    int t = threadIdx.x;
    int loc[7]; int s = 0;
    #pragma unroll
    for (int j = 0; j < 7; j++){
        int idx = t*7 + j;
        int v = (idx < NFINE) ? fineCount[idx] : 0;
        loc[j] = s; s += v;
    }
    part[t] = s;
    __syncthreads();
    if (t == 0){
        int run = 0;
        for (int i = 0; i < 256; i++){ int v = part[i]; part[i] = run; run += v; }
    }
    __syncthreads();
    #pragma unroll
    for (int j = 0; j < 7; j++){
        int idx = t*7 + j;
        if (idx < NFINE){
            int b = part[t] + loc[j];
            shb[idx] = b;
            fineBase[idx]   = b;
            fineCursor[idx] = b;
        }
    }
    __syncthreads();
    if (t < NCOARSE) coarseCursor[t] = shb[t*64];
}

// ----------------- sort pass 1: bin edges into 25 coarse buckets (LDS round compaction) -----------------
__global__ __launch_bounds__(256) void k_binA(const int* __restrict__ ei, int* __restrict__ coarseCursor,
                                              u64* __restrict__ coarseBuf){
    __shared__ int cnt[NCOARSE], gpos[NCOARSE], baseS[NCOARSE+1];
    __shared__ u64 stage[ROUND];
    __shared__ short bkt[ROUND];
    int t = threadIdx.x;
    int chunk = blockIdx.x * ROUND;
    if (t < NCOARSE) cnt[t] = 0;
    __syncthreads();
    u64 ed[8]; int b[8], rk[8];
    #pragma unroll
    for (int j = 0; j < 8; j++){
        int e = chunk + t + j*256;
        unsigned int s = (unsigned int)__builtin_nontemporal_load(&ei[e]);
        unsigned int d = (unsigned int)__builtin_nontemporal_load(&ei[N_EDGESC + e]);
        ed[j] = ((u64)d << 32) | (u64)s;
        b[j] = (int)(d >> 12);
        rk[j] = atomicAdd(&cnt[b[j]], 1);
    }
    __syncthreads();
    if (t == 0){
        int s = 0;
        for (int i = 0; i < NCOARSE; i++){ baseS[i] = s; s += cnt[i]; }
        baseS[NCOARSE] = s;
    }
    __syncthreads();
    if (t < NCOARSE && cnt[t] > 0) gpos[t] = atomicAdd(&coarseCursor[t], cnt[t]);
    __syncthreads();
    #pragma unroll
    for (int j = 0; j < 8; j++){
        int p = baseS[b[j]] + rk[j];
        stage[p] = ed[j];
        bkt[p] = (short)b[j];
    }
    __syncthreads();
    #pragma unroll
    for (int j = 0; j < 8; j++){
        int p = t + j*256;
        int bb = bkt[p];
        coarseBuf[gpos[bb] + (p - baseS[bb])] = stage[p];
    }
}

// ----------------- sort pass 2: coarse -> 64 fine sub-buckets each -----------------
__global__ __launch_bounds__(256) void k_binB(const u64* __restrict__ coarseBuf, const int* __restrict__ fineBase,
                                              int* __restrict__ fineCursor, u64* __restrict__ fineBuf){
    int c   = blockIdx.x >> 5;
    int sub = blockIdx.x & 31;
    int segB = fineBase[c*64];
    int segE = (c == NCOARSE-1) ? N_EDGESC : fineBase[(c+1)*64];
    __shared__ int cnt[64], gpos[64], baseS[65];
    __shared__ u64 stage[ROUND];
    __shared__ short bkt[ROUND];
    int t = threadIdx.x;
    for (int r = sub; ; r += 32){
        int base = segB + r*ROUND;
        if (base >= segE) break;
        int m = segE - base; if (m > ROUND) m = ROUND;
        if (t < 64) cnt[t] = 0;
        __syncthreads();
        u64 ed[8]; int b[8], rk[8], val[8];
        #pragma unroll
        for (int j = 0; j < 8; j++){
            int i = t + j*256;
            val[j] = (i < m);
            if (val[j]){
                ed[j] = __builtin_nontemporal_load(&coarseBuf[base + i]);
                b[j] = (int)((ed[j] >> 38) & 63);
                rk[j] = atomicAdd(&cnt[b[j]], 1);
            }
        }
        __syncthreads();
        if (t == 0){
            int s = 0;
            for (int i = 0; i < 64; i++){ baseS[i] = s; s += cnt[i]; }
            baseS[64] = s;
        }
        __syncthreads();
        if (t < 64 && cnt[t] > 0) gpos[t] = atomicAdd(&fineCursor[c*64 + t], cnt[t]);
        __syncthreads();
        #pragma unroll
        for (int j = 0; j < 8; j++){
            if (val[j]){
                int p = baseS[b[j]] + rk[j];
                stage[p] = ed[j];
                bkt[p] = (short)b[j];
            }
        }
        __syncthreads();
        int total = baseS[64];
        #pragma unroll
        for (int j = 0; j < 8; j++){
            int p = t + j*256;
            if (p < total){
                int bb = bkt[p];
                fineBuf[gpos[bb] + (p - baseS[bb])] = stage[p];
            }
        }
        __syncthreads();
    }
}

// ----------------- sort pass 3: per fine bucket (64 nodes) build CSR + dinv, scatter srcS -----------------
__global__ __launch_bounds__(256) void k_binC(const u64* __restrict__ fineBuf, const int* __restrict__ fineBase,
                                              const int* __restrict__ fineCount, int* __restrict__ row_ptr,
                                              float* __restrict__ dinv, int* __restrict__ srcS){
    int f = blockIdx.x, t = threadIdx.x;
    int gB = fineBase[f];
    int cntE = fineCount[f];
    __shared__ int deg[64], excl[64], cur[64];
    if (t < 64){ deg[t] = 0; cur[t] = 0; }
    __syncthreads();
    for (int i = t; i < cntE; i += 256){
        int lo = (int)((fineBuf[gB + i] >> 32) & 63);
        atomicAdd(&deg[lo], 1);
    }
    __syncthreads();
    if (t == 0){
        int s = 0;
        for (int i = 0; i < 64; i++){ excl[i] = s; s += deg[i]; }
    }
    __syncthreads();
    if (t < 64){
        row_ptr[f*64 + t] = gB + excl[t];
        dinv[f*64 + t] = rsqrtf((float)(deg[t] + 1));
    }
    if (f == 0 && t == 0) row_ptr[N_NODESC] = N_EDGESC;
    for (int i = t; i < cntE; i += 256){
        u64 ed = fineBuf[gB + i];
        int lo = (int)((ed >> 32) & 63);
        int pos = gB + excl[lo] + atomicAdd(&cur[lo], 1);
        srcS[pos] = (int)(unsigned int)(ed & 0xffffffffu);
    }
}

// ----------------- W0^T in bf16 -----------------
__global__ __launch_bounds__(256) void k_prepw0(const float* __restrict__ W, unsigned short* __restrict__ Wt){
    int idx = blockIdx.x*256 + threadIdx.x;
    int n = idx & 127, k = idx >> 7;
    Wt[n*128 + k] = f2bf(W[k*128 + n]);
}

// ----------------- MFMA bf16 GEMM: Hd = bf16(dinv[row] * (X @ W + biasv)) -----------------
template<int F32IN>
__global__ __launch_bounds__(256) void k_gemm_mfma(const void* __restrict__ Xin,
        const unsigned short* __restrict__ Wt, const float* __restrict__ biasv,
        const float* __restrict__ dinv, unsigned short* __restrict__ H){
    int l   = threadIdx.x & 63;
    int wid = threadIdx.x >> 6;
    int R   = blockIdx.x*64 + wid*16;
    int r0  = l & 15;
    int kg  = l >> 4;
    short8 a[4];
    if (F32IN){
        const float* X = (const float*)Xin;
        #pragma unroll
        for (int kk = 0; kk < 4; kk++){
            const float* p = X + (size_t)(R + r0)*HID + kk*32 + kg*8;
            float4 u = *(const float4*)p;
            float4 v = *(const float4*)(p + 4);
            short8 tt;
            tt[0]=(short)f2bf(u.x); tt[1]=(short)f2bf(u.y); tt[2]=(short)f2bf(u.z); tt[3]=(short)f2bf(u.w);
            tt[4]=(short)f2bf(v.x); tt[5]=(short)f2bf(v.y); tt[6]=(short)f2bf(v.z); tt[7]=(short)f2bf(v.w);
            a[kk] = tt;
        }
    } else {
        const unsigned short* X = (const unsigned short*)Xin;
        #pragma unroll
        for (int kk = 0; kk < 4; kk++)
            a[kk] = *(const short8*)(X + (size_t)(R + r0)*HID + kk*32 + kg*8);
    }
    f32x4 acc[8];
    #pragma unroll
    for (int i = 0; i < 8; i++) acc[i] = (f32x4)(0.f);
    #pragma unroll
    for (int kk = 0; kk < 4; kk++){
        #pragma unroll
        for (int nf = 0; nf < 8; nf++){
            short8 b = *(const short8*)(Wt + (size_t)(nf*16 + r0)*HID + kk*32 + kg*8);
            acc[nf] = __builtin_amdgcn_mfma_f32_16x16x32_bf16(a[kk], b, acc[nf], 0, 0, 0);
        }
    }
    float bv[8];
    #pragma unroll
    for (int nf = 0; nf < 8; nf++) bv[nf] = biasv[nf*16 + r0];
    #pragma unroll
    for (int r = 0; r < 4; r++){
        int row = R + kg*4 + r;
        float di = dinv[row];
        #pragma unroll
        for (int nf = 0; nf < 8; nf++)
            H[(size_t)row*HID + nf*16 + r0] = f2bf(di * (acc[nf][r] + bv[nf]));
    }
}

// --------- aggregation + relu + fused BN stats; srcS-only metadata, pre-scaled rows ---------
// OUT[n] = relu( dinv[n] * (sum_e Hd[src_e] + Hd[n]) + b )
__global__ __launch_bounds__(256) void k_agg(const unsigned int* __restrict__ Hb, const int* __restrict__ row_ptr,
                                             const int* __restrict__ srcS, const float* __restrict__ dinv,
                                             const float* __restrict__ bconv,
                                             unsigned int* __restrict__ OUT, float* __restrict__ sum,
                                             float* __restrict__ sumsq){
    int lane = threadIdx.x & 63;
    int w    = threadIdx.x >> 6;
    int wave = blockIdx.x*4 + w;
    int nw   = gridDim.x*4;
    float2 bc = ((const float2*)bconv)[lane];
    float sx0 = 0.f, sx1 = 0.f, sq0 = 0.f, sq1 = 0.f;
    for (int n = wave; n < N_NODESC; n += nw){
        int e0 = row_ptr[n], e1 = row_ptr[n+1];
        unsigned int gn = Hb[(size_t)n*64 + lane];      // self-loop term
        float ax = bflo(gn), ay = bfhi(gn);
        int e = e0;
        while (e < e1 && (e & 3)){
            unsigned int g = Hb[(size_t)srcS[e]*64 + lane];
            ax += bflo(g); ay += bfhi(g);
            e++;
        }
        for (; e + 8 <= e1; e += 8){
            int4 sa = *(const int4*)(srcS + e);
            int4 sb = *(const int4*)(srcS + e + 4);
            unsigned int g0 = Hb[(size_t)sa.x*64 + lane];
            unsigned int g1 = Hb[(size_t)sa.y*64 + lane];
            unsigned int g2 = Hb[(size_t)sa.z*64 + lane];
            unsigned int g3 = Hb[(size_t)sa.w*64 + lane];
            unsigned int g4 = Hb[(size_t)sb.x*64 + lane];
            unsigned int g5 = Hb[(size_t)sb.y*64 + lane];
            unsigned int g6 = Hb[(size_t)sb.z*64 + lane];
            unsigned int g7 = Hb[(size_t)sb.w*64 + lane];
            ax += bflo(g0); ay += bfhi(g0);
            ax += bflo(g1); ay += bfhi(g1);
            ax += bflo(g2); ay += bfhi(g2);
            ax += bflo(g3); ay += bfhi(g3);
            ax += bflo(g4); ay += bfhi(g4);
            ax += bflo(g5); ay += bfhi(g5);
            ax += bflo(g6); ay += bfhi(g6);
            ax += bflo(g7); ay += bfhi(g7);
        }
        if (e + 4 <= e1){
            int4 sa = *(const int4*)(srcS + e);
            unsigned int g0 = Hb[(size_t)sa.x*64 + lane];
            unsigned int g1 = Hb[(size_t)sa.y*64 + lane];
            unsigned int g2 = Hb[(size_t)sa.z*64 + lane];
            unsigned int g3 = Hb[(size_t)sa.w*64 + lane];
            ax += bflo(g0); ay += bfhi(g0);
            ax += bflo(g1); ay += bfhi(g1);
            ax += bflo(g2); ay += bfhi(g2);
            ax += bflo(g3); ay += bfhi(g3);
            e += 4;
        }
        for (; e < e1; e++){
            unsigned int g = Hb[(size_t)srcS[e]*64 + lane];
            ax += bflo(g); ay += bfhi(g);
        }
        float dn = dinv[n];
        ax = fmaxf(fmaf(ax, dn, bc.x), 0.f);
        ay = fmaxf(fmaf(ay, dn, bc.y), 0.f);
        unsigned int o = ((unsigned int)f2bf(ay) << 16) | (unsigned int)f2bf(ax);
        __builtin_nontemporal_store(o, &OUT[(size_t)n*64 + lane]);
        sx0 += ax; sq0 = fmaf(ax, ax, sq0);
        sx1 += ay; sq1 = fmaf(ay, ay, sq1);
    }
    __shared__ float shs[4][128];
    __shared__ float shq[4][128];
    shs[w][2*lane]   = sx0; shs[w][2*lane+1] = sx1;
    shq[w][2*lane]   = sq0; shq[w][2*lane+1] = sq1;
    __syncthreads();
    int t = threadIdx.x;
    if (t < 128){
        atomicAdd(&sum[t],   shs[0][t] + shs[1][t] + shs[2][t] + shs[3][t]);
        atomicAdd(&sumsq[t], shq[0][t] + shq[1][t] + shq[2][t] + shq[3][t]);
    }
}

// ----------------- BN finalize part 1: A, B, folded bias (1 block) -----------------
__global__ __launch_bounds__(128) void k_fin1(const float* __restrict__ sum, const float* __restrict__ sumsq,
                                              const float* __restrict__ gamma, const float* __restrict__ beta,
                                              const float* __restrict__ Wnext, float* __restrict__ A,
                                              float* __restrict__ B, float* __restrict__ biasv, int hasNext){
    __shared__ float Bsh[128];
    int c = threadIdx.x;
    const float invN = 1.0f / (float)N_NODESC;
    float mu  = sum[c] * invN;
    float var = sumsq[c] * invN - mu*mu;
    float is  = rsqrtf(var + BN_EPS);
    float a = is * gamma[c];
    float b = beta[c] - mu * a;
    A[c] = a; B[c] = b; Bsh[c] = b;
    __syncthreads();
    if (hasNext){
        float bv = 0.f;
        for (int k = 0; k < 128; k++)
            bv = fmaf(Bsh[k], Wnext[k*128 + c], bv);
        biasv[c] = bv;
    }
}

// ----------------- BN finalize part 2: parallel W fold, WpT[c][k] = bf16(A[k]*W[k][c]) -----------------
__global__ __launch_bounds__(256) void k_fin2(const float* __restrict__ A, const float* __restrict__ Wnext,
                                              unsigned short* __restrict__ WpT){
    int idx = blockIdx.x*256 + threadIdx.x;
    int c = idx >> 7, k = idx & 127;
    WpT[c*128 + k] = f2bf(A[k] * Wnext[k*128 + c]);
}

// ----------------- readout pooling (max, mean, first), bf16 in, BN applied inline -----------------
__global__ __launch_bounds__(1024) void k_pool(const unsigned short* __restrict__ X, const float* __restrict__ A,
                                               const float* __restrict__ B, float* __restrict__ g){
    __shared__ float shm[8][128];
    __shared__ float shs[8][128];
    int t = threadIdx.x;
    int c = t & 127, sl = t >> 7;
    int gr = blockIdx.x;
    float a = A[c], b = B[c];
    const unsigned short* base = X + ((size_t)gr*NPG + sl*100)*HID;
    float mx = -1e30f, sm = 0.f;
    for (int i = 0; i < 100; i++){
        float v = fmaf(bfu(base[(size_t)i*HID + c]), a, b);
        mx = fmaxf(mx, v); sm += v;
    }
    shm[sl][c] = mx; shs[sl][c] = sm;
    if (sl == 0) g[gr*384 + 256 + c] = fmaf(bfu(base[c]), a, b);
    __syncthreads();
    if (t < 128){
        float m = shm[0][t], s = shs[0][t];
        #pragma unroll
        for (int q = 1; q < 8; q++){ m = fmaxf(m, shm[q][t]); s += shs[q][t]; }
        g[gr*384 + t]       = m;
        g[gr*384 + 128 + t] = s * (1.0f/(float)NPG);
    }
}

// ----------------- MLP + log_softmax -----------------
__global__ __launch_bounds__(512) void k_mlp(const float* __restrict__ g, const float* __restrict__ W1,
                                             const float* __restrict__ b1, const float* __restrict__ W2,
                                             const float* __restrict__ b2, float* __restrict__ out){
    __shared__ float row[384];
    __shared__ float t1[384];
    __shared__ float r0[512], r1[512];
    int t = threadIdx.x, gr = blockIdx.x;
    if (t < 384) row[t] = g[gr*384 + t];
    __syncthreads();
    if (t < 384){
        float acc = b1[t];
        for (int k = 0; k < 384; k++) acc = fmaf(row[k], W1[(size_t)k*384 + t], acc);
        t1[t] = acc;
    }
    __syncthreads();
    float p0 = 0.f, p1 = 0.f;
    if (t < 384){ float v = t1[t]; p0 = v*W2[t*2]; p1 = v*W2[t*2+1]; }
    r0[t] = p0; r1[t] = p1; __syncthreads();
    for (int off = 256; off > 0; off >>= 1){
        if (t < off){ r0[t] += r0[t+off]; r1[t] += r1[t+off]; }
        __syncthreads();
    }
    if (t == 0){
        float o0 = r0[0] + b2[0], o1 = r1[0] + b2[1];
        float m = fmaxf(o0, o1);
        float lse = m + logf(expf(o0 - m) + expf(o1 - m));
        out[gr*2 + 0] = o0 - lse;
        out[gr*2 + 1] = o1 - lse;
    }
}

extern "C" void kernel_launch(void* const* d_in, const int* in_sizes, int n_in,
                              void* d_out, int out_size, void* d_ws, size_t ws_size,
                              hipStream_t stream){
    const float* x     = (const float*)d_in[0];
    const int*   ei    = (const int*)d_in[1];
    const float* Wconv = (const float*)d_in[3];
    const float* bconv = (const float*)d_in[4];
    const float* gamma = (const float*)d_in[5];
    const float* beta  = (const float*)d_in[6];
    const float* W1    = (const float*)d_in[7];
    const float* b1    = (const float*)d_in[8];
    const float* W2    = (const float*)d_in[9];
    const float* b2    = (const float*)d_in[10];
    float* out = (float*)d_out;

    char* p = (char*)d_ws;
    size_t off = 0;
    auto alloc = [&](size_t bytes)->char* {
        char* r = p + off; off += (bytes + 255) & ~(size_t)255; return r;
    };
    unsigned short* buf1 = (unsigned short*)alloc((size_t)N_NODESC*HID*2);  // Hd = bf16(dinv*(x@W+b))
    unsigned short* buf2 = (unsigned short*)alloc((size_t)N_NODESC*HID*2);  // post-agg relu'd bf16
    u64*  coarseBuf  = (u64*)  alloc((size_t)N_EDGESC*8);
    u64*  fineBuf    = (u64*)  alloc((size_t)N_EDGESC*8);
    int*   srcS      = (int*)  alloc((size_t)N_EDGESC*4);
    int*   row_ptr   = (int*)  alloc((size_t)(N_NODESC+1)*4);
    float* dinv      = (float*)alloc((size_t)N_NODESC*4);
    int*   fineCount = (int*)  alloc(NFINE*4);
    int*   fineBase  = (int*)  alloc(NFINE*4);
    int*   fineCursor= (int*)  alloc(NFINE*4);
    int*   coarseCursor=(int*) alloc(NCOARSE*4);
    float* stats   = (float*)alloc(3*2*128*4);
    float* AB      = (float*)alloc(3*2*128*4);
    unsigned short* Wt0 = (unsigned short*)alloc(128*128*2);
    unsigned short* WpT = (unsigned short*)alloc(128*128*2);
    float* biasv   = (float*)alloc(512);
    float* g       = (float*)alloc((size_t)NUM_GRAPHS*384*4);
    (void)ws_size; (void)in_sizes; (void)n_in; (void)out_size;

    hipMemsetAsync(fineCount, 0, NFINE*4, stream);
    hipMemsetAsync(stats, 0, 3*2*128*4, stream);
    hipMemsetAsync(biasv, 0, 512, stream);

    // CSR build via 2-level LDS-staged counting sort
    k_h1   <<<256, 256, 0, stream>>>(ei, fineCount);
    k_scanF<<<1,   256, 0, stream>>>(fineCount, fineBase, fineCursor, coarseCursor);
    k_binA <<<N_EDGESC/ROUND, 256, 0, stream>>>(ei, coarseCursor, coarseBuf);
    k_binB <<<NCOARSE*32, 256, 0, stream>>>(coarseBuf, fineBase, fineCursor, fineBuf);
    k_binC <<<NFINE, 256, 0, stream>>>(fineBuf, fineBase, fineCount, row_ptr, dinv, srcS);
    k_prepw0<<<64, 256, 0, stream>>>(Wconv, Wt0);

    for (int l = 0; l < 3; l++){
        if (l == 0)
            k_gemm_mfma<1><<<N_NODESC/64, 256, 0, stream>>>((const void*)x, Wt0, biasv, dinv, buf1);
        else
            k_gemm_mfma<0><<<N_NODESC/64, 256, 0, stream>>>((const void*)buf2, WpT, biasv, dinv, buf1);
        k_agg<<<2048, 256, 0, stream>>>((const unsigned int*)buf1, row_ptr, srcS, dinv,
                                        bconv + l*HID, (unsigned int*)buf2,
                                        stats + l*256, stats + l*256 + 128);
        k_fin1<<<1, 128, 0, stream>>>(stats + l*256, stats + l*256 + 128,
                                      gamma + l*HID, beta + l*HID,
                                      Wconv + (size_t)(l+1 < 3 ? l+1 : 0)*HID*HID,
                                      AB + l*256, AB + l*256 + 128,
                                      biasv, (l < 2) ? 1 : 0);
        if (l < 2)
            k_fin2<<<64, 256, 0, stream>>>(AB + l*256,
                                           Wconv + (size_t)(l+1)*HID*HID, WpT);
    }
    k_pool<<<NUM_GRAPHS, 1024, 0, stream>>>(buf2, AB + 2*256, AB + 2*256 + 128, g);
    k_mlp <<<NUM_GRAPHS, 512, 0, stream>>>(g, W1, b1, W2, b2, out);
}

// Round 9
// 531.113 us; speedup vs baseline: 1.4157x; 1.0284x over previous
//
#include <hip/hip_runtime.h>
#include <hip/hip_bf16.h>
#include <cstdint>

#define N_NODESC  102400
#define N_EDGESC  1638400
#define NUM_GRAPHS 128
#define NPG       800
#define HID       128
#define BN_EPS    1e-5f

#define NFINE 1600           // fine buckets of 64 nodes
#define NCOARSE 25           // coarse buckets of 4096 nodes
#define ROUND 2048           // edges per binning round

typedef short short8 __attribute__((ext_vector_type(8)));
typedef float f32x4  __attribute__((ext_vector_type(4)));
typedef unsigned long long u64;

__device__ __forceinline__ unsigned short f2bf(float f){
    union { __hip_bfloat16 h; unsigned short u; } cv;
    cv.h = __float2bfloat16(f);
    return cv.u;
}
__device__ __forceinline__ float bflo(unsigned int g){ return __uint_as_float(g << 16); }
__device__ __forceinline__ float bfhi(unsigned int g){ return __uint_as_float(g & 0xffff0000u); }
__device__ __forceinline__ float bfu(unsigned short u){ return __uint_as_float(((unsigned int)u) << 16); }

// ----------------- sort pass 0: fine histogram (1600 buckets of 64 dst nodes) -----------------
__global__ __launch_bounds__(256) void k_h1(const int* __restrict__ ei, int* __restrict__ fineCount){
    __shared__ int h[NFINE];
    int t = threadIdx.x;
    for (int i = t; i < NFINE; i += 256) h[i] = 0;
    __syncthreads();
    for (int e = blockIdx.x*256 + t; e < N_EDGESC; e += gridDim.x*256){
        int d = __builtin_nontemporal_load(&ei[N_EDGESC + e]);
        atomicAdd(&h[d >> 6], 1);
    }
    __syncthreads();
    for (int i = t; i < NFINE; i += 256) if (h[i]) atomicAdd(&fineCount[i], h[i]);
}

// ----------------- sort pass 0b: scan 1600 counts -> bases + cursors (1 block) -----------------
__global__ __launch_bounds__(256) void k_scanF(const int* __restrict__ fineCount, int* __restrict__ fineBase,
                                               int* __restrict__ fineCursor, int* __restrict__ coarseCursor){
    __shared__ int part[256];
    __shared__ int shb[NFINE];
    int t = threadIdx.x;
    int loc[7]; int s = 0;
    #pragma unroll
    for (int j = 0; j < 7; j++){
        int idx = t*7 + j;
        int v = (idx < NFINE) ? fineCount[idx] : 0;
        loc[j] = s; s += v;
    }
    part[t] = s;
    __syncthreads();
    if (t == 0){
        int run = 0;
        for (int i = 0; i < 256; i++){ int v = part[i]; part[i] = run; run += v; }
    }
    __syncthreads();
    #pragma unroll
    for (int j = 0; j < 7; j++){
        int idx = t*7 + j;
        if (idx < NFINE){
            int b = part[t] + loc[j];
            shb[idx] = b;
            fineBase[idx]   = b;
            fineCursor[idx] = b;
        }
    }
    __syncthreads();
    if (t < NCOARSE) coarseCursor[t] = shb[t*64];
}

// ----------------- sort pass 1: bin edges into 25 coarse buckets (LDS round compaction) -----------------
__global__ __launch_bounds__(256) void k_binA(const int* __restrict__ ei, int* __restrict__ coarseCursor,
                                              u64* __restrict__ coarseBuf){
    __shared__ int cnt[NCOARSE], gpos[NCOARSE], baseS[NCOARSE+1];
    __shared__ u64 stage[ROUND];
    __shared__ short bkt[ROUND];
    int t = threadIdx.x;
    int chunk = blockIdx.x * ROUND;
    if (t < NCOARSE) cnt[t] = 0;
    __syncthreads();
    u64 ed[8]; int b[8], rk[8];
    #pragma unroll
    for (int j = 0; j < 8; j++){
        int e = chunk + t + j*256;
        unsigned int s = (unsigned int)__builtin_nontemporal_load(&ei[e]);
        unsigned int d = (unsigned int)__builtin_nontemporal_load(&ei[N_EDGESC + e]);
        ed[j] = ((u64)d << 32) | (u64)s;
        b[j] = (int)(d >> 12);
        rk[j] = atomicAdd(&cnt[b[j]], 1);
    }
    __syncthreads();
    if (t == 0){
        int s = 0;
        for (int i = 0; i < NCOARSE; i++){ baseS[i] = s; s += cnt[i]; }
        baseS[NCOARSE] = s;
    }
    __syncthreads();
    if (t < NCOARSE && cnt[t] > 0) gpos[t] = atomicAdd(&coarseCursor[t], cnt[t]);
    __syncthreads();
    #pragma unroll
    for (int j = 0; j < 8; j++){
        int p = baseS[b[j]] + rk[j];
        stage[p] = ed[j];
        bkt[p] = (short)b[j];
    }
    __syncthreads();
    #pragma unroll
    for (int j = 0; j < 8; j++){
        int p = t + j*256;
        int bb = bkt[p];
        coarseBuf[gpos[bb] + (p - baseS[bb])] = stage[p];
    }
}

// ----------------- sort pass 2: coarse -> 64 fine sub-buckets each -----------------
__global__ __launch_bounds__(256) void k_binB(const u64* __restrict__ coarseBuf, const int* __restrict__ fineBase,
                                              int* __restrict__ fineCursor, u64* __restrict__ fineBuf){
    int c   = blockIdx.x >> 5;
    int sub = blockIdx.x & 31;
    int segB = fineBase[c*64];
    int segE = (c == NCOARSE-1) ? N_EDGESC : fineBase[(c+1)*64];
    __shared__ int cnt[64], gpos[64], baseS[65];
    __shared__ u64 stage[ROUND];
    __shared__ short bkt[ROUND];
    int t = threadIdx.x;
    for (int r = sub; ; r += 32){
        int base = segB + r*ROUND;
        if (base >= segE) break;
        int m = segE - base; if (m > ROUND) m = ROUND;
        if (t < 64) cnt[t] = 0;
        __syncthreads();
        u64 ed[8]; int b[8], rk[8], val[8];
        #pragma unroll
        for (int j = 0; j < 8; j++){
            int i = t + j*256;
            val[j] = (i < m);
            if (val[j]){
                ed[j] = __builtin_nontemporal_load(&coarseBuf[base + i]);
                b[j] = (int)((ed[j] >> 38) & 63);
                rk[j] = atomicAdd(&cnt[b[j]], 1);
            }
        }
        __syncthreads();
        if (t == 0){
            int s = 0;
            for (int i = 0; i < 64; i++){ baseS[i] = s; s += cnt[i]; }
            baseS[64] = s;
        }
        __syncthreads();
        if (t < 64 && cnt[t] > 0) gpos[t] = atomicAdd(&fineCursor[c*64 + t], cnt[t]);
        __syncthreads();
        #pragma unroll
        for (int j = 0; j < 8; j++){
            if (val[j]){
                int p = baseS[b[j]] + rk[j];
                stage[p] = ed[j];
                bkt[p] = (short)b[j];
            }
        }
        __syncthreads();
        int total = baseS[64];
        #pragma unroll
        for (int j = 0; j < 8; j++){
            int p = t + j*256;
            if (p < total){
                int bb = bkt[p];
                fineBuf[gpos[bb] + (p - baseS[bb])] = stage[p];
            }
        }
        __syncthreads();
    }
}

// ----------------- sort pass 3: per fine bucket (64 nodes) build CSR + dinv, scatter srcS -----------------
__global__ __launch_bounds__(256) void k_binC(const u64* __restrict__ fineBuf, const int* __restrict__ fineBase,
                                              const int* __restrict__ fineCount, int* __restrict__ row_ptr,
                                              float* __restrict__ dinv, int* __restrict__ srcS){
    int f = blockIdx.x, t = threadIdx.x;
    int gB = fineBase[f];
    int cntE = fineCount[f];
    __shared__ int deg[64], excl[64], cur[64];
    if (t < 64){ deg[t] = 0; cur[t] = 0; }
    __syncthreads();
    for (int i = t; i < cntE; i += 256){
        int lo = (int)((fineBuf[gB + i] >> 32) & 63);
        atomicAdd(&deg[lo], 1);
    }
    __syncthreads();
    if (t == 0){
        int s = 0;
        for (int i = 0; i < 64; i++){ excl[i] = s; s += deg[i]; }
    }
    __syncthreads();
    if (t < 64){
        row_ptr[f*64 + t] = gB + excl[t];
        dinv[f*64 + t] = rsqrtf((float)(deg[t] + 1));
    }
    if (f == 0 && t == 0) row_ptr[N_NODESC] = N_EDGESC;
    for (int i = t; i < cntE; i += 256){
        u64 ed = fineBuf[gB + i];
        int lo = (int)((ed >> 32) & 63);
        int pos = gB + excl[lo] + atomicAdd(&cur[lo], 1);
        srcS[pos] = (int)(unsigned int)(ed & 0xffffffffu);
    }
}

// ----------------- W0^T in bf16 (+ biasv zero init) -----------------
__global__ __launch_bounds__(256) void k_prepw0(const float* __restrict__ W, unsigned short* __restrict__ Wt,
                                                float* __restrict__ biasv){
    int idx = blockIdx.x*256 + threadIdx.x;
    int n = idx & 127, k = idx >> 7;
    Wt[n*128 + k] = f2bf(W[k*128 + n]);
    if (idx < 128) biasv[idx] = 0.f;
}

// ----------------- MFMA bf16 GEMM: Hd = bf16(dinv[row] * (X @ W + biasv)) -----------------
template<int F32IN>
__global__ __launch_bounds__(256) void k_gemm_mfma(const void* __restrict__ Xin,
        const unsigned short* __restrict__ Wt, const float* __restrict__ biasv,
        const float* __restrict__ dinv, unsigned short* __restrict__ H){
    int l   = threadIdx.x & 63;
    int wid = threadIdx.x >> 6;
    int R   = blockIdx.x*64 + wid*16;
    int r0  = l & 15;
    int kg  = l >> 4;
    short8 a[4];
    if (F32IN){
        const float* X = (const float*)Xin;
        #pragma unroll
        for (int kk = 0; kk < 4; kk++){
            const float* p = X + (size_t)(R + r0)*HID + kk*32 + kg*8;
            float4 u = *(const float4*)p;
            float4 v = *(const float4*)(p + 4);
            short8 tt;
            tt[0]=(short)f2bf(u.x); tt[1]=(short)f2bf(u.y); tt[2]=(short)f2bf(u.z); tt[3]=(short)f2bf(u.w);
            tt[4]=(short)f2bf(v.x); tt[5]=(short)f2bf(v.y); tt[6]=(short)f2bf(v.z); tt[7]=(short)f2bf(v.w);
            a[kk] = tt;
        }
    } else {
        const unsigned short* X = (const unsigned short*)Xin;
        #pragma unroll
        for (int kk = 0; kk < 4; kk++)
            a[kk] = *(const short8*)(X + (size_t)(R + r0)*HID + kk*32 + kg*8);
    }
    f32x4 acc[8];
    #pragma unroll
    for (int i = 0; i < 8; i++) acc[i] = (f32x4)(0.f);
    #pragma unroll
    for (int kk = 0; kk < 4; kk++){
        #pragma unroll
        for (int nf = 0; nf < 8; nf++){
            short8 b = *(const short8*)(Wt + (size_t)(nf*16 + r0)*HID + kk*32 + kg*8);
            acc[nf] = __builtin_amdgcn_mfma_f32_16x16x32_bf16(a[kk], b, acc[nf], 0, 0, 0);
        }
    }
    float bv[8];
    #pragma unroll
    for (int nf = 0; nf < 8; nf++) bv[nf] = biasv[nf*16 + r0];
    #pragma unroll
    for (int r = 0; r < 4; r++){
        int row = R + kg*4 + r;
        float di = dinv[row];
        #pragma unroll
        for (int nf = 0; nf < 8; nf++)
            H[(size_t)row*HID + nf*16 + r0] = f2bf(di * (acc[nf][r] + bv[nf]));
    }
}

// --------- dual-node aggregation + relu + fused BN stats; two independent gather chains/wave ---------
// OUT[n] = relu( dinv[n] * (sum_e Hd[src_e] + Hd[n]) + b )
__global__ __launch_bounds__(256) void k_agg(const unsigned int* __restrict__ Hb, const int* __restrict__ row_ptr,
                                             const int* __restrict__ srcS, const float* __restrict__ dinv,
                                             const float* __restrict__ bconv,
                                             unsigned int* __restrict__ OUT, float* __restrict__ sum,
                                             float* __restrict__ sumsq){
    int lane = threadIdx.x & 63;
    int w    = threadIdx.x >> 6;
    int wave = blockIdx.x*4 + w;
    int nw   = gridDim.x*4;
    float2 bc = ((const float2*)bconv)[lane];
    float sx0 = 0.f, sx1 = 0.f, sq0 = 0.f, sq1 = 0.f;
    const int NPAIR = N_NODESC/2;
    for (int pb = wave; pb < NPAIR; pb += nw){
        int nA = 2*pb, nB = 2*pb + 1;
        int eA  = row_ptr[nA], e1A = row_ptr[nA+1], e1B = row_ptr[nB+1];
        int eB  = e1A;
        // self-loop gathers for both chains
        unsigned int gsA = Hb[(size_t)nA*64 + lane];
        unsigned int gsB = Hb[(size_t)nB*64 + lane];
        float axA = bflo(gsA), ayA = bfhi(gsA);
        float axB = bflo(gsB), ayB = bfhi(gsB);
        // interleaved main loop: 4 gathers per chain in flight
        while (eA + 4 <= e1A && eB + 4 <= e1B){
            int4 sa = *(const int4*)(srcS + eA);
            int4 sb = *(const int4*)(srcS + eB);
            unsigned int g0 = Hb[(size_t)sa.x*64 + lane];
            unsigned int g1 = Hb[(size_t)sa.y*64 + lane];
            unsigned int g2 = Hb[(size_t)sa.z*64 + lane];
            unsigned int g3 = Hb[(size_t)sa.w*64 + lane];
            unsigned int h0 = Hb[(size_t)sb.x*64 + lane];
            unsigned int h1 = Hb[(size_t)sb.y*64 + lane];
            unsigned int h2 = Hb[(size_t)sb.z*64 + lane];
            unsigned int h3 = Hb[(size_t)sb.w*64 + lane];
            axA += bflo(g0); ayA += bfhi(g0);
            axA += bflo(g1); ayA += bfhi(g1);
            axA += bflo(g2); ayA += bfhi(g2);
            axA += bflo(g3); ayA += bfhi(g3);
            axB += bflo(h0); ayB += bfhi(h0);
            axB += bflo(h1); ayB += bfhi(h1);
            axB += bflo(h2); ayB += bfhi(h2);
            axB += bflo(h3); ayB += bfhi(h3);
            eA += 4; eB += 4;
        }
        // drain chain A
        for (; eA + 4 <= e1A; eA += 4){
            int4 sa = *(const int4*)(srcS + eA);
            unsigned int g0 = Hb[(size_t)sa.x*64 + lane];
            unsigned int g1 = Hb[(size_t)sa.y*64 + lane];
            unsigned int g2 = Hb[(size_t)sa.z*64 + lane];
            unsigned int g3 = Hb[(size_t)sa.w*64 + lane];
            axA += bflo(g0); ayA += bfhi(g0);
            axA += bflo(g1); ayA += bfhi(g1);
            axA += bflo(g2); ayA += bfhi(g2);
            axA += bflo(g3); ayA += bfhi(g3);
        }
        // drain chain B
        for (; eB + 4 <= e1B; eB += 4){
            int4 sb = *(const int4*)(srcS + eB);
            unsigned int h0 = Hb[(size_t)sb.x*64 + lane];
            unsigned int h1 = Hb[(size_t)sb.y*64 + lane];
            unsigned int h2 = Hb[(size_t)sb.z*64 + lane];
            unsigned int h3 = Hb[(size_t)sb.w*64 + lane];
            axB += bflo(h0); ayB += bfhi(h0);
            axB += bflo(h1); ayB += bfhi(h1);
            axB += bflo(h2); ayB += bfhi(h2);
            axB += bflo(h3); ayB += bfhi(h3);
        }
        // scalar tails (interleave both)
        while (eA < e1A || eB < e1B){
            unsigned int g = 0, h = 0;
            int doA = (eA < e1A), doB = (eB < e1B);
            if (doA) g = Hb[(size_t)srcS[eA]*64 + lane];
            if (doB) h = Hb[(size_t)srcS[eB]*64 + lane];
            if (doA){ axA += bflo(g); ayA += bfhi(g); eA++; }
            if (doB){ axB += bflo(h); ayB += bfhi(h); eB++; }
        }
        float dA = dinv[nA], dB = dinv[nB];
        axA = fmaxf(fmaf(axA, dA, bc.x), 0.f);
        ayA = fmaxf(fmaf(ayA, dA, bc.y), 0.f);
        axB = fmaxf(fmaf(axB, dB, bc.x), 0.f);
        ayB = fmaxf(fmaf(ayB, dB, bc.y), 0.f);
        unsigned int oA = ((unsigned int)f2bf(ayA) << 16) | (unsigned int)f2bf(axA);
        unsigned int oB = ((unsigned int)f2bf(ayB) << 16) | (unsigned int)f2bf(axB);
        __builtin_nontemporal_store(oA, &OUT[(size_t)nA*64 + lane]);
        __builtin_nontemporal_store(oB, &OUT[(size_t)nB*64 + lane]);
        sx0 += axA + axB; sq0 += axA*axA + axB*axB;
        sx1 += ayA + ayB; sq1 += ayA*ayA + ayB*ayB;
    }
    __shared__ float shs[4][128];
    __shared__ float shq[4][128];
    shs[w][2*lane]   = sx0; shs[w][2*lane+1] = sx1;
    shq[w][2*lane]   = sq0; shq[w][2*lane+1] = sq1;
    __syncthreads();
    int t = threadIdx.x;
    if (t < 128){
        atomicAdd(&sum[t],   shs[0][t] + shs[1][t] + shs[2][t] + shs[3][t]);
        atomicAdd(&sumsq[t], shq[0][t] + shq[1][t] + shq[2][t] + shq[3][t]);
    }
}

// ----------------- BN finalize part 1: A, B, folded bias (1 block) -----------------
__global__ __launch_bounds__(128) void k_fin1(const float* __restrict__ sum, const float* __restrict__ sumsq,
                                              const float* __restrict__ gamma, const float* __restrict__ beta,
                                              const float* __restrict__ Wnext, float* __restrict__ A,
                                              float* __restrict__ B, float* __restrict__ biasv, int hasNext){
    __shared__ float Bsh[128];
    int c = threadIdx.x;
    const float invN = 1.0f / (float)N_NODESC;
    float mu  = sum[c] * invN;
    float var = sumsq[c] * invN - mu*mu;
    float is  = rsqrtf(var + BN_EPS);
    float a = is * gamma[c];
    float b = beta[c] - mu * a;
    A[c] = a; B[c] = b; Bsh[c] = b;
    __syncthreads();
    if (hasNext){
        float bv = 0.f;
        for (int k = 0; k < 128; k++)
            bv = fmaf(Bsh[k], Wnext[k*128 + c], bv);
        biasv[c] = bv;
    }
}

// ----------------- BN finalize part 2: parallel W fold, WpT[c][k] = bf16(A[k]*W[k][c]) -----------------
__global__ __launch_bounds__(256) void k_fin2(const float* __restrict__ A, const float* __restrict__ Wnext,
                                              unsigned short* __restrict__ WpT){
    int idx = blockIdx.x*256 + threadIdx.x;
    int c = idx >> 7, k = idx & 127;
    WpT[c*128 + k] = f2bf(A[k] * Wnext[k*128 + c]);
}

// ----------------- fused readout: pool (max/mean/first w/ BN) + MLP + log_softmax, 1 block/graph -----------------
__global__ __launch_bounds__(512) void k_poolmlp(const unsigned short* __restrict__ X, const float* __restrict__ A,
                                                 const float* __restrict__ B, const float* __restrict__ W1,
                                                 const float* __restrict__ b1, const float* __restrict__ W2,
                                                 const float* __restrict__ b2, float* __restrict__ out){
    __shared__ float shm[4][128];
    __shared__ float shsm[4][128];
    __shared__ float row[384];
    __shared__ float t1[384];
    __shared__ float r0[512], r1[512];
    int t = threadIdx.x, gr = blockIdx.x;
    int c = t & 127, sl = t >> 7;    // 4 slices x 200 nodes
    float a = A[c], b = B[c];
    const unsigned short* base = X + ((size_t)gr*NPG + sl*200)*HID;
    float mx = -1e30f, sm = 0.f;
    for (int i = 0; i < 200; i++){
        float v = fmaf(bfu(base[(size_t)i*HID + c]), a, b);
        mx = fmaxf(mx, v); sm += v;
    }
    shm[sl][c] = mx; shsm[sl][c] = sm;
    if (sl == 0) row[256 + c] = fmaf(bfu(base[c]), a, b);   // first node of graph
    __syncthreads();
    if (t < 128){
        float m = fmaxf(fmaxf(shm[0][t], shm[1][t]), fmaxf(shm[2][t], shm[3][t]));
        float s = shsm[0][t] + shsm[1][t] + shsm[2][t] + shsm[3][t];
        row[t]       = m;
        row[128 + t] = s * (1.0f/(float)NPG);
    }
    __syncthreads();
    if (t < 384){
        float acc = b1[t];
        for (int k = 0; k < 384; k++) acc = fmaf(row[k], W1[(size_t)k*384 + t], acc);
        t1[t] = acc;
    }
    __syncthreads();
    float p0 = 0.f, p1 = 0.f;
    if (t < 384){ float v = t1[t]; p0 = v*W2[t*2]; p1 = v*W2[t*2+1]; }
    r0[t] = p0; r1[t] = p1; __syncthreads();
    for (int off = 256; off > 0; off >>= 1){
        if (t < off){ r0[t] += r0[t+off]; r1[t] += r1[t+off]; }
        __syncthreads();
    }
    if (t == 0){
        float o0 = r0[0] + b2[0], o1 = r1[0] + b2[1];
        float m = fmaxf(o0, o1);
        float lse = m + logf(expf(o0 - m) + expf(o1 - m));
        out[gr*2 + 0] = o0 - lse;
        out[gr*2 + 1] = o1 - lse;
    }
}

extern "C" void kernel_launch(void* const* d_in, const int* in_sizes, int n_in,
                              void* d_out, int out_size, void* d_ws, size_t ws_size,
                              hipStream_t stream){
    const float* x     = (const float*)d_in[0];
    const int*   ei    = (const int*)d_in[1];
    const float* Wconv = (const float*)d_in[3];
    const float* bconv = (const float*)d_in[4];
    const float* gamma = (const float*)d_in[5];
    const float* beta  = (const float*)d_in[6];
    const float* W1    = (const float*)d_in[7];
    const float* b1    = (const float*)d_in[8];
    const float* W2    = (const float*)d_in[9];
    const float* b2    = (const float*)d_in[10];
    float* out = (float*)d_out;

    char* p = (char*)d_ws;
    size_t off = 0;
    auto alloc = [&](size_t bytes)->char* {
        char* r = p + off; off += (bytes + 255) & ~(size_t)255; return r;
    };
    unsigned short* buf1 = (unsigned short*)alloc((size_t)N_NODESC*HID*2);  // Hd = bf16(dinv*(x@W+b))
    unsigned short* buf2 = (unsigned short*)alloc((size_t)N_NODESC*HID*2);  // post-agg relu'd bf16
    u64*  coarseBuf  = (u64*)  alloc((size_t)N_EDGESC*8);
    u64*  fineBuf    = (u64*)  alloc((size_t)N_EDGESC*8);
    int*   srcS      = (int*)  alloc((size_t)N_EDGESC*4);
    int*   row_ptr   = (int*)  alloc((size_t)(N_NODESC+1)*4);
    float* dinv      = (float*)alloc((size_t)N_NODESC*4);
    int*   fineCount = (int*)  alloc(NFINE*4);
    int*   fineBase  = (int*)  alloc(NFINE*4);
    int*   fineCursor= (int*)  alloc(NFINE*4);
    int*   coarseCursor=(int*) alloc(NCOARSE*4);
    float* stats   = (float*)alloc(3*2*128*4);
    float* AB      = (float*)alloc(3*2*128*4);
    unsigned short* Wt0 = (unsigned short*)alloc(128*128*2);
    unsigned short* WpT = (unsigned short*)alloc(128*128*2);
    float* biasv   = (float*)alloc(512);
    (void)ws_size; (void)in_sizes; (void)n_in; (void)out_size;

    hipMemsetAsync(fineCount, 0, NFINE*4, stream);
    hipMemsetAsync(stats, 0, 3*2*128*4, stream);

    // CSR build via 2-level LDS-staged counting sort
    k_h1   <<<256, 256, 0, stream>>>(ei, fineCount);
    k_scanF<<<1,   256, 0, stream>>>(fineCount, fineBase, fineCursor, coarseCursor);
    k_binA <<<N_EDGESC/ROUND, 256, 0, stream>>>(ei, coarseCursor, coarseBuf);
    k_binB <<<NCOARSE*32, 256, 0, stream>>>(coarseBuf, fineBase, fineCursor, fineBuf);
    k_binC <<<NFINE, 256, 0, stream>>>(fineBuf, fineBase, fineCount, row_ptr, dinv, srcS);
    k_prepw0<<<64, 256, 0, stream>>>(Wconv, Wt0, biasv);

    for (int l = 0; l < 3; l++){
        if (l == 0)
            k_gemm_mfma<1><<<N_NODESC/64, 256, 0, stream>>>((const void*)x, Wt0, biasv, dinv, buf1);
        else
            k_gemm_mfma<0><<<N_NODESC/64, 256, 0, stream>>>((const void*)buf2, WpT, biasv, dinv, buf1);
        k_agg<<<2048, 256, 0, stream>>>((const unsigned int*)buf1, row_ptr, srcS, dinv,
                                        bconv + l*HID, (unsigned int*)buf2,
                                        stats + l*256, stats + l*256 + 128);
        k_fin1<<<1, 128, 0, stream>>>(stats + l*256, stats + l*256 + 128,
                                      gamma + l*HID, beta + l*HID,
                                      Wconv + (size_t)(l+1 < 3 ? l+1 : 0)*HID*HID,
                                      AB + l*256, AB + l*256 + 128,
                                      biasv, (l < 2) ? 1 : 0);
        if (l < 2)
            k_fin2<<<64, 256, 0, stream>>>(AB + l*256,
                                           Wconv + (size_t)(l+1)*HID*HID, WpT);
    }
    k_poolmlp<<<NUM_GRAPHS, 512, 0, stream>>>(buf2, AB + 2*256, AB + 2*256 + 128,
                                              W1, b1, W2, b2, out);
}